// Round 1
// baseline (244.247 us; speedup 1.0000x reference)
//
#include <hip/hip_runtime.h>
#include <math.h>

#define NN 384
#define NSQ (NN*NN)          // 147456

// workspace float offsets
#define WS_MASKF 0           // 384
#define WS_C1    384         // 384*8   = 3072
#define WS_P     3456        // 384*512 = 196608
#define WS_VN    200064      // 384*256 = 98304
#define WS_T     298368      // 384*512 = 196608
#define WS_GH    494976      // 64*384  = 24576
// total 519552 floats = ~2.08 MB

// ---------------------------------------------------------------------------
// K0: normalize mask -> float {0,1}. Auto-detects whether the bool mask was
// delivered as int32 (values all 0/1) or packed bytes (some word > 1).
__global__ void k_mask(const unsigned int* __restrict__ mi,
                       float* __restrict__ maskf) {
    __shared__ int bytemode;
    int j = threadIdx.x;
    if (j == 0) bytemode = 0;
    __syncthreads();
    unsigned v = mi[j];
    if (v > 1u) bytemode = 1;   // benign race
    __syncthreads();
    int on;
    if (bytemode) on = (((const unsigned char*)mi)[j] != 0);
    else          on = (v != 0u);
    maskf[j] = on ? 1.0f : 0.0f;
}

// ---------------------------------------------------------------------------
// K1: q/kn/vn projections + c1[h,i] = sum_a q*kn, P[h,c,i] = sum_a q*Wk_edge.
// One block handles 8 columns i.
__global__ __launch_bounds__(256) void k_proj(
    const float* __restrict__ nodes, const float* __restrict__ Wq,
    const float* __restrict__ Wk, const float* __restrict__ Wv,
    float* __restrict__ ws) {
    float* c1_ws = ws + WS_C1;
    float* P_ws  = ws + WS_P;
    float* vn_ws = ws + WS_VN;
    int i0 = blockIdx.x * 8;
    int tid = threadIdx.x;
    __shared__ float nl[128][8];
    __shared__ float q_l[256][8];
    __shared__ float qk_l[256][8];
    for (int idx = tid; idx < 1024; idx += 256) {
        int m = idx >> 3, ii = idx & 7;
        nl[m][ii] = nodes[m * NN + i0 + ii];
    }
    __syncthreads();
    int o = tid;
    float aq[8], ak[8], av[8];
#pragma unroll
    for (int ii = 0; ii < 8; ii++) { aq[ii] = 0.f; ak[ii] = 0.f; av[ii] = 0.f; }
#pragma unroll 4
    for (int m = 0; m < 128; m++) {
        float wq = Wq[o * 128 + m];
        float wk = Wk[o * 192 + m];
        float wv = Wv[o * 192 + m];
#pragma unroll
        for (int ii = 0; ii < 8; ii++) {
            float nv = nl[m][ii];
            aq[ii] = fmaf(wq, nv, aq[ii]);
            ak[ii] = fmaf(wk, nv, ak[ii]);
            av[ii] = fmaf(wv, nv, av[ii]);
        }
    }
#pragma unroll
    for (int ii = 0; ii < 8; ii++) {
        vn_ws[(size_t)(i0 + ii) * 256 + o] = av[ii];
        q_l[o][ii]  = aq[ii];
        qk_l[o][ii] = aq[ii] * ak[ii];
    }
    __syncthreads();
    if (tid < 64) {
        int h = tid >> 3, ii = tid & 7;
        float s = 0.f;
        for (int a = 0; a < 32; a++) s += qk_l[h * 32 + a][ii];
        c1_ws[(i0 + ii) * 8 + h] = s;
    }
    for (int rep = 0; rep < 2; rep++) {
        int idx = rep * 256 + tid;
        int c = idx & 63, h = idx >> 6;
        float ap[8];
#pragma unroll
        for (int ii = 0; ii < 8; ii++) ap[ii] = 0.f;
        for (int a = 0; a < 32; a++) {
            float w = Wk[(h * 32 + a) * 192 + 128 + c];
#pragma unroll
            for (int ii = 0; ii < 8; ii++)
                ap[ii] = fmaf(q_l[h * 32 + a][ii], w, ap[ii]);
        }
#pragma unroll
        for (int ii = 0; ii < 8; ii++)
            P_ws[(size_t)(i0 + ii) * 512 + c * 8 + h] = ap[ii];
    }
}

// ---------------------------------------------------------------------------
// K2: per-row attention. Block = one row i, 512 threads.
// pass1 (lanes=j): sim[h,j] = (c1 + sum_c P[h,c]*e[c,j]) * rsqrt(A), masked.
//   Edge values also cached to LDS as bf16 (62 KB total LDS -> 2 blocks/CU).
// softmax per head (one wave per head, butterfly reduce).
// pass2 (lanes=c): T[h,c] = sum_j s[h,j]*e[c,j], partial per wave, combined.
__global__ __launch_bounds__(512) void k_attn(
    const float* __restrict__ edges, const float* __restrict__ ws_ro,
    float* __restrict__ T_ws) {
    __shared__ __align__(16) unsigned short epad_h[64 * 390];  // 49920 B
    __shared__ __align__(16) float sT2[NN * 8];                // 12288 B
    const float* maskf = ws_ro + WS_MASKF;
    const float* c1w   = ws_ro + WS_C1;
    const float* Pw    = ws_ro + WS_P;
    int i = blockIdx.x;
    int tid = threadIdx.x;
    int wv = tid >> 6, ln = tid & 63;
    float mask_i = maskf[i];

    if (tid < NN) {
        int j = tid;
        const float* eb = edges + (size_t)i * NN + j;
        const float* Pi = Pw + (size_t)i * 512;
        float acc[8];
#pragma unroll
        for (int h = 0; h < 8; h++) acc[h] = 0.f;
#pragma unroll 4
        for (int c = 0; c < 64; c++) {
            float e = eb[(size_t)c * NSQ];
            unsigned u = __float_as_uint(e);
            epad_h[c * 390 + j] =
                (unsigned short)((u + 0x7FFFu + ((u >> 16) & 1u)) >> 16);
            const float* Pc = Pi + c * 8;     // wave-uniform -> s_load
#pragma unroll
            for (int h = 0; h < 8; h++) acc[h] = fmaf(Pc[h], e, acc[h]);
        }
        float mj = maskf[j];
        const float* c1i = c1w + i * 8;
        float sv[8];
#pragma unroll
        for (int h = 0; h < 8; h++) {
            float s = (c1i[h] + acc[h]) * 0.17677669529663687f;
            sv[h] = (mj != 0.0f) ? s : -1e30f;
        }
        *reinterpret_cast<float4*>(&sT2[j * 8])     = make_float4(sv[0], sv[1], sv[2], sv[3]);
        *reinterpret_cast<float4*>(&sT2[j * 8 + 4]) = make_float4(sv[4], sv[5], sv[6], sv[7]);
    }
    __syncthreads();
    { // softmax: wave wv owns head h=wv, lanes cover j = ln + 64k
        int h = wv;
        float v[6];
#pragma unroll
        for (int k = 0; k < 6; k++) v[k] = sT2[(ln + 64 * k) * 8 + h];
        float m = v[0];
#pragma unroll
        for (int k = 1; k < 6; k++) m = fmaxf(m, v[k]);
#pragma unroll
        for (int s = 1; s < 64; s <<= 1) m = fmaxf(m, __shfl_xor(m, s));
        float ex[6]; float sum = 0.f;
#pragma unroll
        for (int k = 0; k < 6; k++) { ex[k] = __expf(v[k] - m); sum += ex[k]; }
#pragma unroll
        for (int s = 1; s < 64; s <<= 1) sum += __shfl_xor(sum, s);
        float fac = mask_i / sum;
#pragma unroll
        for (int k = 0; k < 6; k++) sT2[(ln + 64 * k) * 8 + h] = ex[k] * fac;
    }
    __syncthreads();
    // pass2: wave wv handles j in [48*wv, 48*wv+48), lane = channel c
    float t[8];
#pragma unroll
    for (int h = 0; h < 8; h++) t[h] = 0.f;
    {
        int c = ln;
        int j0 = wv * 48;
        for (int j = j0; j < j0 + 48; j++) {
            float e = __uint_as_float(((unsigned)epad_h[c * 390 + j]) << 16);
            float4 s0 = *reinterpret_cast<const float4*>(&sT2[j * 8]);
            float4 s1 = *reinterpret_cast<const float4*>(&sT2[j * 8 + 4]);
            t[0] = fmaf(s0.x, e, t[0]); t[1] = fmaf(s0.y, e, t[1]);
            t[2] = fmaf(s0.z, e, t[2]); t[3] = fmaf(s0.w, e, t[3]);
            t[4] = fmaf(s1.x, e, t[4]); t[5] = fmaf(s1.y, e, t[5]);
            t[6] = fmaf(s1.z, e, t[6]); t[7] = fmaf(s1.w, e, t[7]);
        }
    }
    __syncthreads();                       // epad_h dead; reuse as partials
    float* Tp = reinterpret_cast<float*>(epad_h);   // 8*512 floats = 16 KB
#pragma unroll
    for (int h = 0; h < 8; h++) Tp[wv * 512 + h * 64 + ln] = t[h];
    __syncthreads();
    {
        int h = tid >> 6, c = tid & 63;
        float s = 0.f;
#pragma unroll
        for (int w = 0; w < 8; w++) s += Tp[w * 512 + h * 64 + c];
        T_ws[(size_t)i * 512 + h * 64 + c] = s;
    }
}

// ---------------------------------------------------------------------------
// K3: nf[d,i] = mask_i*vn + W_v_edge @ T ; node_out = W_o@nf ; g = 0.5*W_e[:, :256]@nf
__global__ __launch_bounds__(256) void k_nf(
    const float* __restrict__ Wv, const float* __restrict__ Wo,
    const float* __restrict__ We, const float* __restrict__ ws_ro,
    float* __restrict__ gh_ws, float* __restrict__ out) {
    const float* maskf = ws_ro + WS_MASKF;
    const float* vn_ws = ws_ro + WS_VN;
    const float* T_ws  = ws_ro + WS_T;
    int i = blockIdx.x, tid = threadIdx.x;
    __shared__ float T_l[512];
    __shared__ float nf_l[256];
    T_l[tid]       = T_ws[(size_t)i * 512 + tid];
    T_l[tid + 256] = T_ws[(size_t)i * 512 + 256 + tid];
    __syncthreads();
    int d = tid, h = d >> 5;
    float a0 = 0.f, a1 = 0.f, a2 = 0.f, a3 = 0.f;
#pragma unroll
    for (int c = 0; c < 64; c += 4) {
        a0 = fmaf(Wv[d * 192 + 128 + c],     T_l[h * 64 + c],     a0);
        a1 = fmaf(Wv[d * 192 + 128 + c + 1], T_l[h * 64 + c + 1], a1);
        a2 = fmaf(Wv[d * 192 + 128 + c + 2], T_l[h * 64 + c + 2], a2);
        a3 = fmaf(Wv[d * 192 + 128 + c + 3], T_l[h * 64 + c + 3], a3);
    }
    nf_l[d] = maskf[i] * vn_ws[(size_t)i * 256 + d] + ((a0 + a1) + (a2 + a3));
    __syncthreads();
    if (tid < 128) {
        int o = tid;
        float b0 = 0.f, b1 = 0.f, b2 = 0.f, b3 = 0.f;
#pragma unroll 8
        for (int dd = 0; dd < 256; dd += 4) {
            b0 = fmaf(Wo[o * 256 + dd],     nf_l[dd],     b0);
            b1 = fmaf(Wo[o * 256 + dd + 1], nf_l[dd + 1], b1);
            b2 = fmaf(Wo[o * 256 + dd + 2], nf_l[dd + 2], b2);
            b3 = fmaf(Wo[o * 256 + dd + 3], nf_l[dd + 3], b3);
        }
        out[o * NN + i] = (b0 + b1) + (b2 + b3);
    } else if (tid < 192) {
        int o = tid - 128;
        float b0 = 0.f, b1 = 0.f, b2 = 0.f, b3 = 0.f;
#pragma unroll 8
        for (int dd = 0; dd < 256; dd += 4) {
            b0 = fmaf(We[o * 320 + dd],     nf_l[dd],     b0);
            b1 = fmaf(We[o * 320 + dd + 1], nf_l[dd + 1], b1);
            b2 = fmaf(We[o * 320 + dd + 2], nf_l[dd + 2], b2);
            b3 = fmaf(We[o * 320 + dd + 3], nf_l[dd + 3], b3);
        }
        gh_ws[o * NN + i] = 0.5f * ((b0 + b1) + (b2 + b3));
    }
}

// ---------------------------------------------------------------------------
// K4: edge_out[o,i,j] = gh[o,i] + gh[o,j] + sum_c W_e[o,256+c]*edges[c,i,j]
// One block per row i, thread = j. e[64] in VGPRs via coalesced loads;
// W row + gh[o,i] wave-uniform -> scalar loads; stores coalesced.
__global__ __launch_bounds__(384) void k_edge(
    const float* __restrict__ edges, const float* __restrict__ We,
    const float* __restrict__ gh_ws, float* __restrict__ out_e) {
    int i = blockIdx.x, j = threadIdx.x;
    float e[64];
    const float* eb = edges + (size_t)i * NN + j;
#pragma unroll
    for (int c = 0; c < 64; c++) e[c] = eb[(size_t)c * NSQ];
    size_t obase = (size_t)i * NN + j;
    for (int o = 0; o < 64; o++) {
        float gi = gh_ws[o * NN + i];          // uniform
        float gj = gh_ws[o * NN + j];          // coalesced
        const float* wr = We + o * 320 + 256;  // uniform row -> s_load
        float a0 = gi + gj, a1 = 0.f, a2 = 0.f, a3 = 0.f;
#pragma unroll
        for (int c = 0; c < 64; c += 4) {
            a0 = fmaf(wr[c],     e[c],     a0);
            a1 = fmaf(wr[c + 1], e[c + 1], a1);
            a2 = fmaf(wr[c + 2], e[c + 2], a2);
            a3 = fmaf(wr[c + 3], e[c + 3], a3);
        }
        out_e[(size_t)o * NSQ + obase] = (a0 + a1) + (a2 + a3);
    }
}

// ---------------------------------------------------------------------------
extern "C" void kernel_launch(void* const* d_in, const int* in_sizes, int n_in,
                              void* d_out, int out_size, void* d_ws, size_t ws_size,
                              hipStream_t stream) {
    const float* nodes = (const float*)d_in[0];
    const float* edges = (const float*)d_in[1];
    const unsigned int* mask = (const unsigned int*)d_in[2];
    const float* Wq = (const float*)d_in[3];
    const float* Wk = (const float*)d_in[4];
    const float* Wv = (const float*)d_in[5];
    const float* Wo = (const float*)d_in[6];
    const float* We = (const float*)d_in[7];
    float* out = (float*)d_out;
    float* ws  = (float*)d_ws;

    hipLaunchKernelGGL(k_mask, dim3(1), dim3(384), 0, stream, mask, ws + WS_MASKF);
    hipLaunchKernelGGL(k_proj, dim3(48), dim3(256), 0, stream, nodes, Wq, Wk, Wv, ws);
    hipLaunchKernelGGL(k_attn, dim3(384), dim3(512), 0, stream, edges, ws, ws + WS_T);
    hipLaunchKernelGGL(k_nf, dim3(384), dim3(256), 0, stream, Wv, Wo, We, ws,
                       ws + WS_GH, out);
    hipLaunchKernelGGL(k_edge, dim3(384), dim3(384), 0, stream, edges, We,
                       ws + WS_GH, out + 128 * NN);
}

// Round 2
// 195.429 us; speedup vs baseline: 1.2498x; 1.2498x over previous
//
#include <hip/hip_runtime.h>
#include <math.h>

#define NN 384
#define NSQ (NN*NN)          // 147456

// workspace float offsets
#define WS_MASKF 0           // 384
#define WS_C1    384         // 384*8   = 3072
#define WS_P     3456        // 384*512 = 196608
#define WS_VN    200064      // 384*256 = 98304
#define WS_T     298368      // 384*512 = 196608
#define WS_GH    494976      // 64*384  = 24576
// total 519552 floats = ~2.08 MB

// ---------------------------------------------------------------------------
// K0: normalize mask -> float {0,1}. Auto-detects whether the bool mask was
// delivered as int32 (values all 0/1) or packed bytes (some word > 1).
__global__ void k_mask(const unsigned int* __restrict__ mi,
                       float* __restrict__ maskf) {
    __shared__ int bytemode;
    int j = threadIdx.x;
    if (j == 0) bytemode = 0;
    __syncthreads();
    unsigned v = mi[j];
    if (v > 1u) bytemode = 1;   // benign race
    __syncthreads();
    int on;
    if (bytemode) on = (((const unsigned char*)mi)[j] != 0);
    else          on = (v != 0u);
    maskf[j] = on ? 1.0f : 0.0f;
}

// ---------------------------------------------------------------------------
// K1: q/kn/vn projections + c1[h,i] = sum_a q*kn, P[h,c,i] = sum_a q*Wk_edge.
// One block handles 8 columns i.
__global__ __launch_bounds__(256) void k_proj(
    const float* __restrict__ nodes, const float* __restrict__ Wq,
    const float* __restrict__ Wk, const float* __restrict__ Wv,
    float* __restrict__ ws) {
    float* c1_ws = ws + WS_C1;
    float* P_ws  = ws + WS_P;
    float* vn_ws = ws + WS_VN;
    int i0 = blockIdx.x * 8;
    int tid = threadIdx.x;
    __shared__ float nl[128][8];
    __shared__ float q_l[256][8];
    __shared__ float qk_l[256][8];
    for (int idx = tid; idx < 1024; idx += 256) {
        int m = idx >> 3, ii = idx & 7;
        nl[m][ii] = nodes[m * NN + i0 + ii];
    }
    __syncthreads();
    int o = tid;
    float aq[8], ak[8], av[8];
#pragma unroll
    for (int ii = 0; ii < 8; ii++) { aq[ii] = 0.f; ak[ii] = 0.f; av[ii] = 0.f; }
#pragma unroll 4
    for (int m = 0; m < 128; m++) {
        float wq = Wq[o * 128 + m];
        float wk = Wk[o * 192 + m];
        float wv = Wv[o * 192 + m];
#pragma unroll
        for (int ii = 0; ii < 8; ii++) {
            float nv = nl[m][ii];
            aq[ii] = fmaf(wq, nv, aq[ii]);
            ak[ii] = fmaf(wk, nv, ak[ii]);
            av[ii] = fmaf(wv, nv, av[ii]);
        }
    }
#pragma unroll
    for (int ii = 0; ii < 8; ii++) {
        vn_ws[(size_t)(i0 + ii) * 256 + o] = av[ii];
        q_l[o][ii]  = aq[ii];
        qk_l[o][ii] = aq[ii] * ak[ii];
    }
    __syncthreads();
    if (tid < 64) {
        int h = tid >> 3, ii = tid & 7;
        float s = 0.f;
        for (int a = 0; a < 32; a++) s += qk_l[h * 32 + a][ii];
        c1_ws[(i0 + ii) * 8 + h] = s;
    }
    for (int rep = 0; rep < 2; rep++) {
        int idx = rep * 256 + tid;
        int c = idx & 63, h = idx >> 6;
        float ap[8];
#pragma unroll
        for (int ii = 0; ii < 8; ii++) ap[ii] = 0.f;
        for (int a = 0; a < 32; a++) {
            float w = Wk[(h * 32 + a) * 192 + 128 + c];
#pragma unroll
            for (int ii = 0; ii < 8; ii++)
                ap[ii] = fmaf(q_l[h * 32 + a][ii], w, ap[ii]);
        }
#pragma unroll
        for (int ii = 0; ii < 8; ii++)
            P_ws[(size_t)(i0 + ii) * 512 + c * 8 + h] = ap[ii];
    }
}

// ---------------------------------------------------------------------------
// K2: per-row attention. Block = one row i, 512 threads.
// pass1 (lanes=j): sim[h,j] = (c1 + sum_c P[h,c]*e[c,j]) * rsqrt(A), masked.
//   Edge values also cached to LDS as bf16 (62 KB total LDS -> 2 blocks/CU).
// softmax per head (one wave per head, butterfly reduce).
// pass2 (lanes=c): T[h,c] = sum_j s[h,j]*e[c,j], partial per wave, combined.
__global__ __launch_bounds__(512) void k_attn(
    const float* __restrict__ edges, const float* __restrict__ ws_ro,
    float* __restrict__ T_ws) {
    __shared__ __align__(16) unsigned short epad_h[64 * 390];  // 49920 B
    __shared__ __align__(16) float sT2[NN * 8];                // 12288 B
    const float* maskf = ws_ro + WS_MASKF;
    const float* c1w   = ws_ro + WS_C1;
    const float* Pw    = ws_ro + WS_P;
    int i = blockIdx.x;
    int tid = threadIdx.x;
    int wv = tid >> 6, ln = tid & 63;
    float mask_i = maskf[i];

    if (tid < NN) {
        int j = tid;
        const float* eb = edges + (size_t)i * NN + j;
        const float* Pi = Pw + (size_t)i * 512;
        float acc[8];
#pragma unroll
        for (int h = 0; h < 8; h++) acc[h] = 0.f;
#pragma unroll 4
        for (int c = 0; c < 64; c++) {
            float e = eb[(size_t)c * NSQ];
            unsigned u = __float_as_uint(e);
            epad_h[c * 390 + j] =
                (unsigned short)((u + 0x7FFFu + ((u >> 16) & 1u)) >> 16);
            const float* Pc = Pi + c * 8;     // wave-uniform -> s_load
#pragma unroll
            for (int h = 0; h < 8; h++) acc[h] = fmaf(Pc[h], e, acc[h]);
        }
        float mj = maskf[j];
        const float* c1i = c1w + i * 8;
        float sv[8];
#pragma unroll
        for (int h = 0; h < 8; h++) {
            float s = (c1i[h] + acc[h]) * 0.17677669529663687f;
            sv[h] = (mj != 0.0f) ? s : -1e30f;
        }
        *reinterpret_cast<float4*>(&sT2[j * 8])     = make_float4(sv[0], sv[1], sv[2], sv[3]);
        *reinterpret_cast<float4*>(&sT2[j * 8 + 4]) = make_float4(sv[4], sv[5], sv[6], sv[7]);
    }
    __syncthreads();
    { // softmax: wave wv owns head h=wv, lanes cover j = ln + 64k
        int h = wv;
        float v[6];
#pragma unroll
        for (int k = 0; k < 6; k++) v[k] = sT2[(ln + 64 * k) * 8 + h];
        float m = v[0];
#pragma unroll
        for (int k = 1; k < 6; k++) m = fmaxf(m, v[k]);
#pragma unroll
        for (int s = 1; s < 64; s <<= 1) m = fmaxf(m, __shfl_xor(m, s));
        float ex[6]; float sum = 0.f;
#pragma unroll
        for (int k = 0; k < 6; k++) { ex[k] = __expf(v[k] - m); sum += ex[k]; }
#pragma unroll
        for (int s = 1; s < 64; s <<= 1) sum += __shfl_xor(sum, s);
        float fac = mask_i / sum;
#pragma unroll
        for (int k = 0; k < 6; k++) sT2[(ln + 64 * k) * 8 + h] = ex[k] * fac;
    }
    __syncthreads();
    // pass2: wave wv handles j in [48*wv, 48*wv+48), lane = channel c
    float t[8];
#pragma unroll
    for (int h = 0; h < 8; h++) t[h] = 0.f;
    {
        int c = ln;
        int j0 = wv * 48;
        for (int j = j0; j < j0 + 48; j++) {
            float e = __uint_as_float(((unsigned)epad_h[c * 390 + j]) << 16);
            float4 s0 = *reinterpret_cast<const float4*>(&sT2[j * 8]);
            float4 s1 = *reinterpret_cast<const float4*>(&sT2[j * 8 + 4]);
            t[0] = fmaf(s0.x, e, t[0]); t[1] = fmaf(s0.y, e, t[1]);
            t[2] = fmaf(s0.z, e, t[2]); t[3] = fmaf(s0.w, e, t[3]);
            t[4] = fmaf(s1.x, e, t[4]); t[5] = fmaf(s1.y, e, t[5]);
            t[6] = fmaf(s1.z, e, t[6]); t[7] = fmaf(s1.w, e, t[7]);
        }
    }
    __syncthreads();                       // epad_h dead; reuse as partials
    float* Tp = reinterpret_cast<float*>(epad_h);   // 8*512 floats = 16 KB
#pragma unroll
    for (int h = 0; h < 8; h++) Tp[wv * 512 + h * 64 + ln] = t[h];
    __syncthreads();
    {
        int h = tid >> 6, c = tid & 63;
        float s = 0.f;
#pragma unroll
        for (int w = 0; w < 8; w++) s += Tp[w * 512 + h * 64 + c];
        T_ws[(size_t)i * 512 + h * 64 + c] = s;
    }
}

// ---------------------------------------------------------------------------
// K3: nf[d,i] = mask_i*vn + W_v_edge @ T ; node_out = W_o@nf ; g = 0.5*W_e[:, :256]@nf
__global__ __launch_bounds__(256) void k_nf(
    const float* __restrict__ Wv, const float* __restrict__ Wo,
    const float* __restrict__ We, const float* __restrict__ ws_ro,
    float* __restrict__ gh_ws, float* __restrict__ out) {
    const float* maskf = ws_ro + WS_MASKF;
    const float* vn_ws = ws_ro + WS_VN;
    const float* T_ws  = ws_ro + WS_T;
    int i = blockIdx.x, tid = threadIdx.x;
    __shared__ float T_l[512];
    __shared__ float nf_l[256];
    T_l[tid]       = T_ws[(size_t)i * 512 + tid];
    T_l[tid + 256] = T_ws[(size_t)i * 512 + 256 + tid];
    __syncthreads();
    int d = tid, h = d >> 5;
    float a0 = 0.f, a1 = 0.f, a2 = 0.f, a3 = 0.f;
#pragma unroll
    for (int c = 0; c < 64; c += 4) {
        a0 = fmaf(Wv[d * 192 + 128 + c],     T_l[h * 64 + c],     a0);
        a1 = fmaf(Wv[d * 192 + 128 + c + 1], T_l[h * 64 + c + 1], a1);
        a2 = fmaf(Wv[d * 192 + 128 + c + 2], T_l[h * 64 + c + 2], a2);
        a3 = fmaf(Wv[d * 192 + 128 + c + 3], T_l[h * 64 + c + 3], a3);
    }
    nf_l[d] = maskf[i] * vn_ws[(size_t)i * 256 + d] + ((a0 + a1) + (a2 + a3));
    __syncthreads();
    if (tid < 128) {
        int o = tid;
        float b0 = 0.f, b1 = 0.f, b2 = 0.f, b3 = 0.f;
#pragma unroll 8
        for (int dd = 0; dd < 256; dd += 4) {
            b0 = fmaf(Wo[o * 256 + dd],     nf_l[dd],     b0);
            b1 = fmaf(Wo[o * 256 + dd + 1], nf_l[dd + 1], b1);
            b2 = fmaf(Wo[o * 256 + dd + 2], nf_l[dd + 2], b2);
            b3 = fmaf(Wo[o * 256 + dd + 3], nf_l[dd + 3], b3);
        }
        out[o * NN + i] = (b0 + b1) + (b2 + b3);
    } else if (tid < 192) {
        int o = tid - 128;
        float b0 = 0.f, b1 = 0.f, b2 = 0.f, b3 = 0.f;
#pragma unroll 8
        for (int dd = 0; dd < 256; dd += 4) {
            b0 = fmaf(We[o * 320 + dd],     nf_l[dd],     b0);
            b1 = fmaf(We[o * 320 + dd + 1], nf_l[dd + 1], b1);
            b2 = fmaf(We[o * 320 + dd + 2], nf_l[dd + 2], b2);
            b3 = fmaf(We[o * 320 + dd + 3], nf_l[dd + 3], b3);
        }
        gh_ws[o * NN + i] = 0.5f * ((b0 + b1) + (b2 + b3));
    }
}

// ---------------------------------------------------------------------------
// K4: edge_out[o,i,j] = gh[o,i] + gh[o,j] + sum_c W_e[o,256+c]*edges[c,i,j]
// Block = (row i, o-group og of 16 o's); thread = j. e[64] in VGPRs via
// coalesced loads; gj[16] prefetched to registers BEFORE the o-loop (removes
// the per-o dependent global load that serialized the old version); W row +
// gh[o,i] are blockIdx-uniform -> scalar loads. grid 384x4 = 9216 waves for
// latency hiding (old: 2304).
__global__ __launch_bounds__(384) void k_edge(
    const float* __restrict__ edges, const float* __restrict__ We,
    const float* __restrict__ gh_ws, float* __restrict__ out_e) {
    int i = blockIdx.x, og = blockIdx.y, j = threadIdx.x;
    float e[64];
    const float* eb = edges + (size_t)i * NN + j;
#pragma unroll
    for (int c = 0; c < 64; c++) e[c] = eb[(size_t)c * NSQ];
    float gj[16];
    const float* gb = gh_ws + og * 16 * NN + j;
#pragma unroll
    for (int oi = 0; oi < 16; oi++) gj[oi] = gb[oi * NN];
    size_t obase = (size_t)i * NN + j;
#pragma unroll 2
    for (int oi = 0; oi < 16; oi++) {
        int o = og * 16 + oi;
        float gi = gh_ws[o * NN + i];          // uniform -> s_load
        const float* wr = We + o * 320 + 256;  // uniform row -> s_load
        float a0 = gi + gj[oi], a1 = 0.f, a2 = 0.f, a3 = 0.f;
#pragma unroll
        for (int c = 0; c < 64; c += 4) {
            a0 = fmaf(wr[c],     e[c],     a0);
            a1 = fmaf(wr[c + 1], e[c + 1], a1);
            a2 = fmaf(wr[c + 2], e[c + 2], a2);
            a3 = fmaf(wr[c + 3], e[c + 3], a3);
        }
        out_e[(size_t)o * NSQ + obase] = (a0 + a1) + (a2 + a3);
    }
}

// ---------------------------------------------------------------------------
extern "C" void kernel_launch(void* const* d_in, const int* in_sizes, int n_in,
                              void* d_out, int out_size, void* d_ws, size_t ws_size,
                              hipStream_t stream) {
    const float* nodes = (const float*)d_in[0];
    const float* edges = (const float*)d_in[1];
    const unsigned int* mask = (const unsigned int*)d_in[2];
    const float* Wq = (const float*)d_in[3];
    const float* Wk = (const float*)d_in[4];
    const float* Wv = (const float*)d_in[5];
    const float* Wo = (const float*)d_in[6];
    const float* We = (const float*)d_in[7];
    float* out = (float*)d_out;
    float* ws  = (float*)d_ws;

    hipLaunchKernelGGL(k_mask, dim3(1), dim3(384), 0, stream, mask, ws + WS_MASKF);
    hipLaunchKernelGGL(k_proj, dim3(48), dim3(256), 0, stream, nodes, Wq, Wk, Wv, ws);
    hipLaunchKernelGGL(k_attn, dim3(384), dim3(512), 0, stream, edges, ws, ws + WS_T);
    hipLaunchKernelGGL(k_nf, dim3(384), dim3(256), 0, stream, Wv, Wo, We, ws,
                       ws + WS_GH, out);
    hipLaunchKernelGGL(k_edge, dim3(384, 4), dim3(384), 0, stream, edges, We,
                       ws + WS_GH, out + 128 * NN);
}